// Round 1
// baseline (1666.399 us; speedup 1.0000x reference)
//
#include <hip/hip_runtime.h>
#include <hip/hip_bf16.h>
#include <math.h>

// ---------------------------------------------------------------------------
// Problem: Graft_StackedDense
//   W0 = blend(w0, g0, p0)           [512,1024]
//   W1 = blend(w1, g1, p1)           [1,512]
//   out = relu(x @ W0^T + b0) @ W1^T + b1     x:[65536,1024] -> out:[65536,1]
//
// Round 0: correctness-first fp32. Entropy histogram replicated with exact
// fp32 boundary arithmetic (no FMA contraction). Main GEMM fused with the
// final GEMV so the [65536,512] hidden activation never hits memory.
// ---------------------------------------------------------------------------

#define B_BIG 65536
#define D_IN 1024
#define D_H 512

// ws layout (in 4-byte words):
//  [0..3]   ent[4]          (float)  e_w0, e_g0, e_w1, e_g1
//  [4..11]  minmax uint[8]  (min_a at 4+2a, max_a at 5+2a, orderable-uint)
//  [16..55] counts[4][10]   (uint)
//  [64 ..]  W0b float[512*1024]
//  [64+524288 ..] W1b float[512]
#define WS_ENT 0
#define WS_MM 4
#define WS_CNT 16
#define WS_W0B 64
#define WS_W1B (64 + 512 * 1024)

__device__ __forceinline__ unsigned f2ord(float f) {
    unsigned u = __float_as_uint(f);
    return (u & 0x80000000u) ? ~u : (u | 0x80000000u);
}
__device__ __forceinline__ float ord2f(unsigned k) {
    unsigned u = (k & 0x80000000u) ? (k ^ 0x80000000u) : ~k;
    return __uint_as_float(u);
}

// softmax-weight for base, given d (pre-sigmoid) and w_global
__device__ __forceinline__ float blend_factor(float d, float wg) {
    float wl = 1.0f / (1.0f + expf(-d));
    float wb = wg * (1.0f - expf(-wg * wl));
    float wgr = (1.0f - wg) * (1.0f - expf(-(1.0f - wg) * (1.0f - wl)));
    return 1.0f / (1.0f + expf(-(wb - wgr)));
}

__device__ __forceinline__ float wglobal_from_ent(float eb, float eg) {
    // 0.4/pi * atan(500*(eb-eg)) + 0.5
    return 0.12732395447351627f * atanf(500.0f * (eb - eg)) + 0.5f;
}

// ---------------------------------------------------------------------------
__global__ void init_ws_kernel(unsigned* ws_u) {
    int t = threadIdx.x;
    if (t < 4) {
        ws_u[WS_MM + 2 * t] = 0xFFFFFFFFu;  // min slot (orderable): +inf
        ws_u[WS_MM + 2 * t + 1] = 0u;       // max slot: -inf
    }
    if (t >= WS_CNT && t < WS_CNT + 40) ws_u[t] = 0u;
}

// ---------------------------------------------------------------------------
// blockIdx.x: 0..63 -> w0 chunks, 64..127 -> g0 chunks, 128 -> w1, 129 -> g1
__device__ __forceinline__ void array_map(int bx, const float* w0, const float* g0,
                                          const float* w1, const float* g1,
                                          int& a, const float*& arr, int& per, int& start) {
    if (bx < 64) { a = 0; arr = w0; per = 524288 / 64; start = bx * per; }
    else if (bx < 128) { a = 1; arr = g0; per = 524288 / 64; start = (bx - 64) * per; }
    else if (bx == 128) { a = 2; arr = w1; per = 512; start = 0; }
    else { a = 3; arr = g1; per = 512; start = 0; }
}

__global__ __launch_bounds__(256) void minmax_kernel(const float* __restrict__ w0,
                                                     const float* __restrict__ g0,
                                                     const float* __restrict__ w1,
                                                     const float* __restrict__ g1,
                                                     unsigned* ws_u) {
    int a, per, start;
    const float* arr;
    array_map(blockIdx.x, w0, g0, w1, g1, a, arr, per, start);
    float mn = INFINITY, mx = -INFINITY;
    for (int i = threadIdx.x; i < per; i += 256) {
        float v = arr[start + i];
        mn = fminf(mn, v);
        mx = fmaxf(mx, v);
    }
#pragma unroll
    for (int off = 32; off > 0; off >>= 1) {
        mn = fminf(mn, __shfl_xor(mn, off));
        mx = fmaxf(mx, __shfl_xor(mx, off));
    }
    __shared__ float smn[4], smx[4];
    int wave = threadIdx.x >> 6, lane = threadIdx.x & 63;
    if (lane == 0) { smn[wave] = mn; smx[wave] = mx; }
    __syncthreads();
    if (threadIdx.x == 0) {
        mn = fminf(fminf(smn[0], smn[1]), fminf(smn[2], smn[3]));
        mx = fmaxf(fmaxf(smx[0], smx[1]), fmaxf(smx[2], smx[3]));
        atomicMin(&ws_u[WS_MM + 2 * a], f2ord(mn));
        atomicMax(&ws_u[WS_MM + 2 * a + 1], f2ord(mx));
    }
}

__global__ __launch_bounds__(256) void hist_kernel(const float* __restrict__ w0,
                                                   const float* __restrict__ g0,
                                                   const float* __restrict__ w1,
                                                   const float* __restrict__ g1,
                                                   unsigned* ws_u) {
    int a, per, start;
    const float* arr;
    array_map(blockIdx.x, w0, g0, w1, g1, a, arr, per, start);
    float lo = ord2f(ws_u[WS_MM + 2 * a]);
    float hi = ord2f(ws_u[WS_MM + 2 * a + 1]);
    float scale = __fdiv_rn(__fsub_rn(hi, lo), 10.0f);
    __shared__ float lower[11];
    __shared__ unsigned cnt[10];
    if (threadIdx.x < 11)
        lower[threadIdx.x] = __fadd_rn(lo, __fmul_rn((float)threadIdx.x, scale));
    if (threadIdx.x < 10) cnt[threadIdx.x] = 0u;
    __syncthreads();
    float inv_scale = 1.0f / scale;  // guess only; exact compares below
    for (int i = threadIdx.x; i < per; i += 256) {
        float v = arr[start + i];
        int g = (int)floorf((v - lo) * inv_scale);
#pragma unroll
        for (int db = -1; db <= 1; db++) {
            int b = g + db;
            if (b >= 0 && b <= 9 && v >= lower[b] && v < lower[b + 1])
                atomicAdd(&cnt[b], 1u);
        }
    }
    __syncthreads();
    if (threadIdx.x < 10 && cnt[threadIdx.x] > 0)
        atomicAdd(&ws_u[WS_CNT + a * 10 + threadIdx.x], cnt[threadIdx.x]);
}

__global__ void finalize_ent_kernel(unsigned* ws_u) {
    int a = threadIdx.x;
    if (a < 4) {
        float n = (a < 2) ? 524288.0f : 512.0f;
        float ent = 0.0f;
        for (int i = 0; i < 10; i++) {
            float p = __fdiv_rn((float)ws_u[WS_CNT + a * 10 + i], n);
            if (p > 0.0f) ent = __fsub_rn(ent, __fmul_rn(p, logf(p)));
        }
        ((float*)ws_u)[WS_ENT + a] = ent;
    }
}

// ---------------------------------------------------------------------------
// W0 blend: d[o,i] = sum_k |w0[o,k]-g0[o,k]| * p0[i,k]   (o<512, i<1024, K=1024)
// 64x64 tile, BK=16, 256 threads, 4x4 per thread.
__global__ __launch_bounds__(256) void blend0_kernel(const float* __restrict__ w0,
                                                     const float* __restrict__ g0,
                                                     const float* __restrict__ p0,
                                                     float* __restrict__ ws_f) {
    __shared__ float As[64][17];
    __shared__ float Bs[64][17];
    float* W0b = ws_f + WS_W0B;
    int tid = threadIdx.x;
    int bo = blockIdx.y * 64;  // o (512)
    int bi = blockIdx.x * 64;  // i (1024)
    int tx = tid & 15, ty = tid >> 4;
    float acc[4][4] = {};
    for (int k0 = 0; k0 < 1024; k0 += 16) {
#pragma unroll
        for (int l = 0; l < 4; l++) {
            int t = tid + l * 256;
            int r = t >> 4, c = t & 15;
            float av = w0[(bo + r) * 1024 + k0 + c] - g0[(bo + r) * 1024 + k0 + c];
            As[r][c] = fabsf(av);
            Bs[r][c] = p0[(bi + r) * 1024 + k0 + c];
        }
        __syncthreads();
#pragma unroll
        for (int k = 0; k < 16; k++) {
            float av[4], bv[4];
#pragma unroll
            for (int r = 0; r < 4; r++) av[r] = As[ty * 4 + r][k];
#pragma unroll
            for (int c = 0; c < 4; c++) bv[c] = Bs[tx * 4 + c][k];
#pragma unroll
            for (int r = 0; r < 4; r++)
#pragma unroll
                for (int c = 0; c < 4; c++) acc[r][c] += av[r] * bv[c];
        }
        __syncthreads();
    }
    float wg = wglobal_from_ent(ws_f[WS_ENT + 0], ws_f[WS_ENT + 1]);
#pragma unroll
    for (int r = 0; r < 4; r++) {
#pragma unroll
        for (int c = 0; c < 4; c++) {
            int o = bo + ty * 4 + r, i = bi + tx * 4 + c;
            float s0 = blend_factor(acc[r][c], wg);
            W0b[o * 1024 + i] = w0[o * 1024 + i] * s0 + g0[o * 1024 + i] * (1.0f - s0);
        }
    }
}

// W1 blend: d[i] = sum_k |w1[k]-g1[k]| * p1[i,k]   (i<512, K=512)
// one wave per output; 128 blocks x 4 waves.
__global__ __launch_bounds__(256) void blend1_kernel(const float* __restrict__ w1,
                                                     const float* __restrict__ g1,
                                                     const float* __restrict__ p1,
                                                     float* __restrict__ ws_f) {
    __shared__ float diff[512];
    float* W1b = ws_f + WS_W1B;
    int tid = threadIdx.x;
    for (int i = tid; i < 512; i += 256) diff[i] = fabsf(w1[i] - g1[i]);
    __syncthreads();
    int wave = tid >> 6, lane = tid & 63;
    int i = blockIdx.x * 4 + wave;
    float acc = 0.0f;
#pragma unroll
    for (int j = 0; j < 8; j++) {
        int k = lane + 64 * j;
        acc += diff[k] * p1[i * 512 + k];
    }
#pragma unroll
    for (int off = 32; off > 0; off >>= 1) acc += __shfl_xor(acc, off);
    if (lane == 0) {
        float wg = wglobal_from_ent(ws_f[WS_ENT + 2], ws_f[WS_ENT + 3]);
        float s0 = blend_factor(acc, wg);
        W1b[i] = w1[i] * s0 + g1[i] * (1.0f - s0);
    }
}

// ---------------------------------------------------------------------------
// Main fused kernel: per block, 32 rows of x, all 512 hidden cols.
// acc[r][j] over K=1024 through LDS; epilogue: bias+relu+*W1b, reduce over h.
// Thread map: cg = tid%32 handles cols h = cg + 32*j (j<16); rg = tid/32 rows rg*4..+3.
__global__ __launch_bounds__(256) void main_kernel(const float* __restrict__ x,
                                                   const float* __restrict__ b0,
                                                   const float* __restrict__ b1,
                                                   const float* __restrict__ ws_f,
                                                   float* __restrict__ out) {
    const float* W0b = ws_f + WS_W0B;
    const float* W1b = ws_f + WS_W1B;
    __shared__ float Xs[32][8];
    __shared__ float Ws[512][9];  // [h][k], pad 9 -> bank = (9h+k)%32, conflict-free
    int tid = threadIdx.x;
    int row0 = blockIdx.x * 32;
    int cg = tid & 31;
    int rg = tid >> 5;
    float acc[4][16];
#pragma unroll
    for (int r = 0; r < 4; r++)
#pragma unroll
        for (int j = 0; j < 16; j++) acc[r][j] = 0.0f;

    for (int k0 = 0; k0 < 1024; k0 += 8) {
        // x tile: 32x8, one float per thread, addr==tid in LDS (no conflicts)
        {
            int r = tid >> 3, c = tid & 7;
            Xs[r][c] = x[(row0 + r) * 1024 + k0 + c];
        }
        // W tile: 512x8 via float4 global loads, scalar LDS stores (<=2-way)
#pragma unroll
        for (int l = 0; l < 4; l++) {
            int t = tid + l * 256;  // 0..1023
            int h = t >> 1, c4 = (t & 1) * 4;
            const float4 v = *(const float4*)(&W0b[h * 1024 + k0 + c4]);
            Ws[h][c4 + 0] = v.x;
            Ws[h][c4 + 1] = v.y;
            Ws[h][c4 + 2] = v.z;
            Ws[h][c4 + 3] = v.w;
        }
        __syncthreads();
#pragma unroll
        for (int k = 0; k < 8; k++) {
            float a[4];
#pragma unroll
            for (int r = 0; r < 4; r++) a[r] = Xs[rg * 4 + r][k];
#pragma unroll
            for (int j = 0; j < 16; j++) {
                float b = Ws[cg + 32 * j][k];
#pragma unroll
                for (int r = 0; r < 4; r++) acc[r][j] += a[r] * b;
            }
        }
        __syncthreads();
    }
    // epilogue: bias + relu + scale by W1b, partial sums per row
    float partial[4] = {0.0f, 0.0f, 0.0f, 0.0f};
#pragma unroll
    for (int j = 0; j < 16; j++) {
        int h = cg + 32 * j;
        float bias = b0[h];
        float wv = W1b[h];
#pragma unroll
        for (int r = 0; r < 4; r++) {
            float y = acc[r][j] + bias;
            y = fmaxf(y, 0.0f);
            partial[r] += y * wv;
        }
    }
    // reduce across 32 column-groups (lanes 0..31 / 32..63 are separate rg's)
#pragma unroll
    for (int off = 16; off > 0; off >>= 1)
#pragma unroll
        for (int r = 0; r < 4; r++) partial[r] += __shfl_xor(partial[r], off);
    if (cg == 0) {
        float bb = b1[0];
#pragma unroll
        for (int r = 0; r < 4; r++) out[row0 + rg * 4 + r] = partial[r] + bb;
    }
}

// ---------------------------------------------------------------------------
extern "C" void kernel_launch(void* const* d_in, const int* in_sizes, int n_in,
                              void* d_out, int out_size, void* d_ws, size_t ws_size,
                              hipStream_t stream) {
    const float* x = (const float*)d_in[0];
    const float* w0 = (const float*)d_in[1];
    const float* b0 = (const float*)d_in[2];
    const float* w1 = (const float*)d_in[3];
    const float* b1 = (const float*)d_in[4];
    const float* p0 = (const float*)d_in[5];
    const float* p1 = (const float*)d_in[6];
    const float* g0 = (const float*)d_in[7];
    const float* g1 = (const float*)d_in[8];
    float* out = (float*)d_out;
    unsigned* ws_u = (unsigned*)d_ws;
    float* ws_f = (float*)d_ws;

    init_ws_kernel<<<1, 64, 0, stream>>>(ws_u);
    minmax_kernel<<<130, 256, 0, stream>>>(w0, g0, w1, g1, ws_u);
    hist_kernel<<<130, 256, 0, stream>>>(w0, g0, w1, g1, ws_u);
    finalize_ent_kernel<<<1, 64, 0, stream>>>(ws_u);
    blend0_kernel<<<dim3(16, 8), 256, 0, stream>>>(w0, g0, p0, ws_f);
    blend1_kernel<<<128, 256, 0, stream>>>(w1, g1, p1, ws_f);
    main_kernel<<<65536 / 32, 256, 0, stream>>>(x, b0, b1, ws_f, out);
}

// Round 2
// 627.393 us; speedup vs baseline: 2.6561x; 2.6561x over previous
//
#include <hip/hip_runtime.h>
#include <hip/hip_bf16.h>
#include <math.h>

// ---------------------------------------------------------------------------
// Graft_StackedDense:
//   W0 = blend(w0, g0, p0)  [512,1024]   W1 = blend(w1, g1, p1)  [1,512]
//   out = relu(x @ W0^T + b0) @ W1^T + b1,  x:[65536,1024] fp32
//
// R1: main GEMM in bf16 MFMA (16x16x32), 128x128 tile, BK=32, m97 structure:
// B (blended W0, bf16 in ws) staged via global_load_lds width=16; A (x fp32)
// staged via float4 loads + cvt->bf16 + ds_write_b128 into padded LDS.
// Layer-2 GEMV fused into the epilogue via shuffle-reduce + atomicAdd.
// ---------------------------------------------------------------------------

typedef __attribute__((ext_vector_type(8))) short short8;
typedef __attribute__((ext_vector_type(4))) float floatx4;
typedef unsigned short ushort_t;

#define WS_ENT 0
#define WS_MM 4
#define WS_CNT 16
#define WS_W0B_WORD 64                    // bf16 W0b: 512*1024 ushorts = 262144 words
#define WS_W1B_WORD (64 + 262144)         // float W1b[512]

__device__ __forceinline__ unsigned f2ord(float f) {
    unsigned u = __float_as_uint(f);
    return (u & 0x80000000u) ? ~u : (u | 0x80000000u);
}
__device__ __forceinline__ float ord2f(unsigned k) {
    unsigned u = (k & 0x80000000u) ? (k ^ 0x80000000u) : ~k;
    return __uint_as_float(u);
}
__device__ __forceinline__ short f2bf(float f) {
    union { __hip_bfloat16 h; short s; } u;
    u.h = __float2bfloat16(f);
    return u.s;
}
__device__ __forceinline__ float blend_factor(float d, float wg) {
    float wl = 1.0f / (1.0f + expf(-d));
    float wb = wg * (1.0f - expf(-wg * wl));
    float wgr = (1.0f - wg) * (1.0f - expf(-(1.0f - wg) * (1.0f - wl)));
    return 1.0f / (1.0f + expf(-(wb - wgr)));
}
__device__ __forceinline__ float wglobal_from_ent(float eb, float eg) {
    return 0.12732395447351627f * atanf(500.0f * (eb - eg)) + 0.5f;
}
__device__ __forceinline__ void async16(const void* g, void* s) {
    __builtin_amdgcn_global_load_lds(
        (const __attribute__((address_space(1))) unsigned int*)g,
        (__attribute__((address_space(3))) unsigned int*)s, 16, 0, 0);
}

// ---------------------------------------------------------------------------
__global__ void init_kernel(unsigned* ws_u, float* out, const float* __restrict__ b1) {
    int gid = blockIdx.x * 256 + threadIdx.x;
    out[gid] = b1[0];
    if (blockIdx.x == 0) {
        int t = threadIdx.x;
        if (t < 4) {
            ws_u[WS_MM + 2 * t] = 0xFFFFFFFFu;
            ws_u[WS_MM + 2 * t + 1] = 0u;
        }
        if (t >= WS_CNT && t < WS_CNT + 40) ws_u[t] = 0u;
    }
}

// ---------------------------------------------------------------------------
__device__ __forceinline__ void array_map(int bx, const float* w0, const float* g0,
                                          const float* w1, const float* g1,
                                          int& a, const float*& arr, int& per, int& start) {
    if (bx < 64) { a = 0; arr = w0; per = 524288 / 64; start = bx * per; }
    else if (bx < 128) { a = 1; arr = g0; per = 524288 / 64; start = (bx - 64) * per; }
    else if (bx == 128) { a = 2; arr = w1; per = 512; start = 0; }
    else { a = 3; arr = g1; per = 512; start = 0; }
}

__global__ __launch_bounds__(256) void minmax_kernel(const float* __restrict__ w0,
                                                     const float* __restrict__ g0,
                                                     const float* __restrict__ w1,
                                                     const float* __restrict__ g1,
                                                     unsigned* ws_u) {
    int a, per, start;
    const float* arr;
    array_map(blockIdx.x, w0, g0, w1, g1, a, arr, per, start);
    float mn = INFINITY, mx = -INFINITY;
    for (int i = threadIdx.x; i < per; i += 256) {
        float v = arr[start + i];
        mn = fminf(mn, v);
        mx = fmaxf(mx, v);
    }
#pragma unroll
    for (int off = 32; off > 0; off >>= 1) {
        mn = fminf(mn, __shfl_xor(mn, off));
        mx = fmaxf(mx, __shfl_xor(mx, off));
    }
    __shared__ float smn[4], smx[4];
    int wave = threadIdx.x >> 6, lane = threadIdx.x & 63;
    if (lane == 0) { smn[wave] = mn; smx[wave] = mx; }
    __syncthreads();
    if (threadIdx.x == 0) {
        mn = fminf(fminf(smn[0], smn[1]), fminf(smn[2], smn[3]));
        mx = fmaxf(fmaxf(smx[0], smx[1]), fmaxf(smx[2], smx[3]));
        atomicMin(&ws_u[WS_MM + 2 * a], f2ord(mn));
        atomicMax(&ws_u[WS_MM + 2 * a + 1], f2ord(mx));
    }
}

__global__ __launch_bounds__(256) void hist_kernel(const float* __restrict__ w0,
                                                   const float* __restrict__ g0,
                                                   const float* __restrict__ w1,
                                                   const float* __restrict__ g1,
                                                   unsigned* ws_u) {
    int a, per, start;
    const float* arr;
    array_map(blockIdx.x, w0, g0, w1, g1, a, arr, per, start);
    float lo = ord2f(ws_u[WS_MM + 2 * a]);
    float hi = ord2f(ws_u[WS_MM + 2 * a + 1]);
    float scale = __fdiv_rn(__fsub_rn(hi, lo), 10.0f);
    __shared__ float lower[11];
    __shared__ unsigned cnt[10];
    if (threadIdx.x < 11)
        lower[threadIdx.x] = __fadd_rn(lo, __fmul_rn((float)threadIdx.x, scale));
    if (threadIdx.x < 10) cnt[threadIdx.x] = 0u;
    __syncthreads();
    float inv_scale = 1.0f / scale;
    for (int i = threadIdx.x; i < per; i += 256) {
        float v = arr[start + i];
        int g = (int)floorf((v - lo) * inv_scale);
#pragma unroll
        for (int db = -1; db <= 1; db++) {
            int b = g + db;
            if (b >= 0 && b <= 9 && v >= lower[b] && v < lower[b + 1])
                atomicAdd(&cnt[b], 1u);
        }
    }
    __syncthreads();
    if (threadIdx.x < 10 && cnt[threadIdx.x] > 0)
        atomicAdd(&ws_u[WS_CNT + a * 10 + threadIdx.x], cnt[threadIdx.x]);
}

__global__ void finalize_ent_kernel(unsigned* ws_u) {
    int a = threadIdx.x;
    if (a < 4) {
        float n = (a < 2) ? 524288.0f : 512.0f;
        float ent = 0.0f;
        for (int i = 0; i < 10; i++) {
            float p = __fdiv_rn((float)ws_u[WS_CNT + a * 10 + i], n);
            if (p > 0.0f) ent = __fsub_rn(ent, __fmul_rn(p, logf(p)));
        }
        ((float*)ws_u)[WS_ENT + a] = ent;
    }
}

// ---------------------------------------------------------------------------
// W0 blend: d[o,i] = sum_k |w0[o,k]-g0[o,k]| * p0[i,k]; output W0b as bf16.
__global__ __launch_bounds__(256) void blend0_kernel(const float* __restrict__ w0,
                                                     const float* __restrict__ g0,
                                                     const float* __restrict__ p0,
                                                     const float* __restrict__ ws_f,
                                                     ushort_t* __restrict__ W0bb) {
    __shared__ float As[64][17];
    __shared__ float Bs[64][17];
    int tid = threadIdx.x;
    int bo = blockIdx.y * 64;  // o (512)
    int bi = blockIdx.x * 64;  // i (1024)
    int tx = tid & 15, ty = tid >> 4;
    int lr = tid >> 2, lc = (tid & 3) * 4;
    float acc[4][4] = {};
    for (int k0 = 0; k0 < 1024; k0 += 16) {
        float4 vw = *(const float4*)&w0[(bo + lr) * 1024 + k0 + lc];
        float4 vg = *(const float4*)&g0[(bo + lr) * 1024 + k0 + lc];
        float4 vp = *(const float4*)&p0[(bi + lr) * 1024 + k0 + lc];
        As[lr][lc + 0] = fabsf(vw.x - vg.x);
        As[lr][lc + 1] = fabsf(vw.y - vg.y);
        As[lr][lc + 2] = fabsf(vw.z - vg.z);
        As[lr][lc + 3] = fabsf(vw.w - vg.w);
        Bs[lr][lc + 0] = vp.x;
        Bs[lr][lc + 1] = vp.y;
        Bs[lr][lc + 2] = vp.z;
        Bs[lr][lc + 3] = vp.w;
        __syncthreads();
#pragma unroll
        for (int k = 0; k < 16; k++) {
            float av[4], bv[4];
#pragma unroll
            for (int r = 0; r < 4; r++) av[r] = As[ty * 4 + r][k];
#pragma unroll
            for (int c = 0; c < 4; c++) bv[c] = Bs[tx * 4 + c][k];
#pragma unroll
            for (int r = 0; r < 4; r++)
#pragma unroll
                for (int c = 0; c < 4; c++) acc[r][c] += av[r] * bv[c];
        }
        __syncthreads();
    }
    float wg = wglobal_from_ent(ws_f[WS_ENT + 0], ws_f[WS_ENT + 1]);
#pragma unroll
    for (int r = 0; r < 4; r++) {
#pragma unroll
        for (int c = 0; c < 4; c++) {
            int o = bo + ty * 4 + r, i = bi + tx * 4 + c;
            float s0 = blend_factor(acc[r][c], wg);
            float v = w0[o * 1024 + i] * s0 + g0[o * 1024 + i] * (1.0f - s0);
            W0bb[o * 1024 + i] = (ushort_t)f2bf(v);
        }
    }
}

// W1 blend (fp32, tiny)
__global__ __launch_bounds__(256) void blend1_kernel(const float* __restrict__ w1,
                                                     const float* __restrict__ g1,
                                                     const float* __restrict__ p1,
                                                     const float* __restrict__ ws_f,
                                                     float* __restrict__ W1b) {
    __shared__ float diff[512];
    int tid = threadIdx.x;
    for (int i = tid; i < 512; i += 256) diff[i] = fabsf(w1[i] - g1[i]);
    __syncthreads();
    int wave = tid >> 6, lane = tid & 63;
    int i = blockIdx.x * 4 + wave;
    float acc = 0.0f;
#pragma unroll
    for (int j = 0; j < 8; j++) {
        int k = lane + 64 * j;
        acc += diff[k] * p1[i * 512 + k];
    }
#pragma unroll
    for (int off = 32; off > 0; off >>= 1) acc += __shfl_xor(acc, off);
    if (lane == 0) {
        float wg = wglobal_from_ent(ws_f[WS_ENT + 2], ws_f[WS_ENT + 3]);
        float s0 = blend_factor(acc, wg);
        W1b[i] = w1[i] * s0 + g1[i] * (1.0f - s0);
    }
}

// ---------------------------------------------------------------------------
// Main MFMA kernel. Block = 128(M) x 128(N) of hidden H, BK=32, 256 threads.
// 4 waves in 2x2; each wave: 4x4 grid of 16x16x32 MFMA tiles (64x64).
// Epilogue: relu(acc+b0)*W1b, reduce 16-lane col groups, atomicAdd to out.
__global__ __launch_bounds__(256) void main_mfma(const float* __restrict__ x,
                                                 const float* __restrict__ b0,
                                                 const ushort_t* __restrict__ W0bb,
                                                 const float* __restrict__ W1b,
                                                 float* __restrict__ out) {
    __shared__ ushort_t As[128 * 40];  // [row][k] bf16, row stride 40 (pad 8)
    __shared__ ushort_t Bs[128 * 32];  // [h][k] bf16, unpadded (global_load_lds)
    int tid = threadIdx.x;
    int w = tid >> 6, l = tid & 63;
    int row0 = blockIdx.x * 128, col0 = blockIdx.y * 128;
    int wm = w & 1, wn = w >> 1;
    int m_in = l & 15, kq = l >> 4;

    floatx4 acc[4][4];
    const floatx4 zero = {0.0f, 0.0f, 0.0f, 0.0f};
#pragma unroll
    for (int tm = 0; tm < 4; tm++)
#pragma unroll
        for (int tn = 0; tn < 4; tn++) acc[tm][tn] = zero;

    // A staging mapping: thread t -> row t>>1, k-chunk (t&1)*16
    int arow = tid >> 1;
    int acol = (tid & 1) * 16;
    const float* xbase = x + (size_t)(row0 + arow) * 1024 + acol;
    ushort_t* awr = &As[arow * 40 + acol];
    // B async mapping: r in {0,1}: h = r*64 + w*16 + (l>>2), kc = (l&3)*8
    const ushort_t* bsrc0 = W0bb + (size_t)(col0 + w * 16 + (l >> 2)) * 1024 + (l & 3) * 8;
    const ushort_t* bsrc1 = bsrc0 + (size_t)64 * 1024;
    ushort_t* bdst0 = &Bs[w * 512];          // + lane*16B implicit
    ushort_t* bdst1 = &Bs[2048 + w * 512];

#pragma unroll 1
    for (int k0 = 0; k0 < 1024; k0 += 32) {
        // async B: 8KB tile, 2 insts/thread, width 16
        async16(bsrc0 + k0, bdst0);
        async16(bsrc1 + k0, bdst1);
        // A: 16 floats -> 16 bf16 -> 2 ds_write_b128
        float4 v0 = *(const float4*)(xbase + k0);
        float4 v1 = *(const float4*)(xbase + k0 + 4);
        float4 v2 = *(const float4*)(xbase + k0 + 8);
        float4 v3 = *(const float4*)(xbase + k0 + 12);
        short8 s0, s1;
        s0[0] = f2bf(v0.x); s0[1] = f2bf(v0.y); s0[2] = f2bf(v0.z); s0[3] = f2bf(v0.w);
        s0[4] = f2bf(v1.x); s0[5] = f2bf(v1.y); s0[6] = f2bf(v1.z); s0[7] = f2bf(v1.w);
        s1[0] = f2bf(v2.x); s1[1] = f2bf(v2.y); s1[2] = f2bf(v2.z); s1[3] = f2bf(v2.w);
        s1[4] = f2bf(v3.x); s1[5] = f2bf(v3.y); s1[6] = f2bf(v3.z); s1[7] = f2bf(v3.w);
        *(short8*)(awr) = s0;
        *(short8*)(awr + 8) = s1;
        __syncthreads();  // drains vmcnt (async B) + lgkm (A writes)
        short8 af[4], bfr[4];
#pragma unroll
        for (int tm = 0; tm < 4; tm++)
            af[tm] = *(const short8*)&As[(wm * 64 + tm * 16 + m_in) * 40 + kq * 8];
#pragma unroll
        for (int tn = 0; tn < 4; tn++)
            bfr[tn] = *(const short8*)&Bs[(wn * 64 + tn * 16 + m_in) * 32 + kq * 8];
#pragma unroll
        for (int tm = 0; tm < 4; tm++)
#pragma unroll
            for (int tn = 0; tn < 4; tn++)
                acc[tm][tn] = __builtin_amdgcn_mfma_f32_16x16x32_bf16(
                    af[tm], bfr[tn], acc[tm][tn], 0, 0, 0);
        __syncthreads();  // protect LDS before next staging
    }

    // epilogue: per (tm,reg): row = row0+wm*64+tm*16+kq*4+reg
    // cols h = col0+wn*64+tn*16+m_in
    float b0v[4], w1v[4];
#pragma unroll
    for (int tn = 0; tn < 4; tn++) {
        int h = col0 + wn * 64 + tn * 16 + m_in;
        b0v[tn] = b0[h];
        w1v[tn] = W1b[h];
    }
#pragma unroll
    for (int tm = 0; tm < 4; tm++) {
#pragma unroll
        for (int reg = 0; reg < 4; reg++) {
            float s = 0.0f;
#pragma unroll
            for (int tn = 0; tn < 4; tn++) {
                float y = acc[tm][tn][reg] + b0v[tn];
                y = fmaxf(y, 0.0f);
                s += y * w1v[tn];
            }
            s += __shfl_xor(s, 1);
            s += __shfl_xor(s, 2);
            s += __shfl_xor(s, 4);
            s += __shfl_xor(s, 8);
            if (m_in == 0)
                atomicAdd(&out[row0 + wm * 64 + tm * 16 + kq * 4 + reg], s);
        }
    }
}

// ---------------------------------------------------------------------------
extern "C" void kernel_launch(void* const* d_in, const int* in_sizes, int n_in,
                              void* d_out, int out_size, void* d_ws, size_t ws_size,
                              hipStream_t stream) {
    const float* x = (const float*)d_in[0];
    const float* w0 = (const float*)d_in[1];
    const float* b0 = (const float*)d_in[2];
    const float* w1 = (const float*)d_in[3];
    const float* b1 = (const float*)d_in[4];
    const float* p0 = (const float*)d_in[5];
    const float* p1 = (const float*)d_in[6];
    const float* g0 = (const float*)d_in[7];
    const float* g1 = (const float*)d_in[8];
    float* out = (float*)d_out;
    unsigned* ws_u = (unsigned*)d_ws;
    float* ws_f = (float*)d_ws;
    ushort_t* W0bb = (ushort_t*)(ws_u + WS_W0B_WORD);
    float* W1b = ws_f + WS_W1B_WORD;

    init_kernel<<<256, 256, 0, stream>>>(ws_u, out, b1);
    minmax_kernel<<<130, 256, 0, stream>>>(w0, g0, w1, g1, ws_u);
    hist_kernel<<<130, 256, 0, stream>>>(w0, g0, w1, g1, ws_u);
    finalize_ent_kernel<<<1, 64, 0, stream>>>(ws_u);
    blend0_kernel<<<dim3(16, 8), 256, 0, stream>>>(w0, g0, p0, ws_f, W0bb);
    blend1_kernel<<<128, 256, 0, stream>>>(w1, g1, p1, ws_f, W1b);
    main_mfma<<<dim3(512, 4), 256, 0, stream>>>(x, b0, W0bb, W1b, out);
}